// Round 6
// baseline (157.679 us; speedup 1.0000x reference)
//
#include <hip/hip_runtime.h>
#include <math.h>

// Problem constants: D=8, H=64, W=64 -> 32768 pixels, 1024 gaussians
#define NG    1024
#define KD    256        // representation feature dim
#define NPIX  32768      // D*H*W
#define BLOCK 512

#define LN2PI_15  2.7568155996140185f   // 1.5 * ln(2*pi)
#define LOG2E     1.4426950408889634f
#define SQH_L2E   0.8493218f            // sqrt(0.5 * log2(e))

typedef float f4v __attribute__((ext_vector_type(4)));

__device__ __forceinline__ float softplus_f(float x) {
    // stable: max(x,0) + log1p(exp(-|x|)) — matches jax.nn.softplus
    return fmaxf(x, 0.0f) + log1pf(expf(-fabsf(x)));
}

__device__ __forceinline__ float exp2_fast(float x) {
#if __has_builtin(__builtin_amdgcn_exp2f)
    return __builtin_amdgcn_exp2f(x);     // v_exp_f32
#else
    float r; asm("v_exp_f32 %0, %1" : "=v"(r) : "v"(x)); return r;
#endif
}

// R6: best-known structure (R1/R4: single kernel, exp computed once per pixel,
// register cache), unpinned (R1 proved compiler's allocation is fine; 64-VGPR
// pins in R2/R3 caused hot-loop spills), PLUS nontemporal float4 stores:
// output is write-once-never-read, so bypass L2/L3 allocation. This is the
// discriminating experiment: if store cache-routing was the hidden ~40us,
// dur drops to ~120; if we're harness-overhead-bound (fill ~85us + restores
// + graph overhead ~= 125-130us fixed), dur stays ~150 and the kernel is at
// the 128MiB write roofline (~20us) + ~5us compute.
//  - NO max pass: L >= log2 => lp <= -1.66, exp can't overflow; shift cancels
//    in normalization (validated R3-R5: absmax 2.4e-4).
//  - exp2 domain: solves pre-scaled by sqrt(0.5*log2e); pass-1 per-pixel body
//    is fma, fma, exp2, add. Normalization folded into one scale multiply.
//  - thread t owns pixels 4t+k+2048i (k<4, i<16): 16 nontemporal float4
//    stores per thread, 1KB contiguous per wave instruction.
__global__ __launch_bounds__(BLOCK)
void mvn_profile_kernel(const float* __restrict__ rep,
                        const float* __restrict__ mean_W,
                        const float* __restrict__ mean_b,
                        const float* __restrict__ scale_W,
                        const float* __restrict__ scale_b,
                        float* __restrict__ out)
{
    const int g = blockIdx.x;   // one block per gaussian
    const int t = threadIdx.x;

    __shared__ float s_part[9][4];  // per-wave partials for the 9 dot products
    __shared__ float s_par[10];     // mx,my,mz, r00,L10,r11,L20,L21,r22s, c0
    __shared__ float s_red[8];      // per-wave reduction scratch (8 waves)

    // ---- prelude: 9 dot-products of length 256 (threads 0..255 = waves 0..3) ----
    if (t < KD) {
        float r = rep[g * KD + t];
        float acc9[9];
        #pragma unroll
        for (int k = 0; k < 3; ++k) acc9[k]     = r * mean_W[k * KD + t];
        #pragma unroll
        for (int k = 0; k < 6; ++k) acc9[3 + k] = r * scale_W[k * KD + t];
        #pragma unroll
        for (int k = 0; k < 9; ++k) {
            float v = acc9[k];
            #pragma unroll
            for (int off = 32; off >= 1; off >>= 1)
                v += __shfl_xor(v, off, 64);
            if ((t & 63) == 0) s_part[k][t >> 6] = v;
        }
    }
    __syncthreads();
    if (t == 0) {
        float dsum[9];
        #pragma unroll
        for (int k = 0; k < 9; ++k)
            dsum[k] = (s_part[k][0] + s_part[k][1]) + (s_part[k][2] + s_part[k][3]);
        float mx = dsum[0] + mean_b[0];
        float my = dsum[1] + mean_b[1];
        float mz = dsum[2] + mean_b[2];
        float s0 = softplus_f(dsum[3] + scale_b[0]) + 1e-6f;
        float s1 = softplus_f(dsum[4] + scale_b[1]) + 1e-6f;
        float s2 = softplus_f(dsum[5] + scale_b[2]) + 1e-6f;
        float s3 = softplus_f(dsum[6] + scale_b[3]) + 1e-6f;
        float s4 = softplus_f(dsum[7] + scale_b[4]) + 1e-6f;
        float s5 = softplus_f(dsum[8] + scale_b[5]) + 1e-6f;
        float L00 = softplus_f(s0);
        float L11 = softplus_f(s2);
        float L22 = softplus_f(s5);
        s_par[0] = mx; s_par[1] = my; s_par[2] = mz;
        s_par[3] = 1.0f / L00;
        s_par[4] = s1;                          // L10
        s_par[5] = 1.0f / L11;
        s_par[6] = s3;                          // L20
        s_par[7] = s4;                          // L21
        s_par[8] = SQH_L2E / L22;               // r22s = sqrt(0.5*log2e)/L22
        // c0 = log2e * (-logdet - 1.5*ln(2pi))
        s_par[9] = -LOG2E * (logf(L00) + logf(L11) + logf(L22) + LN2PI_15);
    }
    __syncthreads();
    const float mx   = s_par[0], my  = s_par[1], mz  = s_par[2];
    const float r00  = s_par[3], L10 = s_par[4], r11 = s_par[5];
    const float L20  = s_par[6], L21 = s_par[7], r22s = s_par[8];
    const float c0   = s_par[9];

    // ---- per-thread constants: k=0..3 (x = 4*(t&15)+k), fsel=0/1 (fy = (t>>4)+32*fsel)
    const float xb = (float)(4 * (t & 15)) - 31.5f - mx;
    const float f0 = (float)(t >> 4);
    float urs[8], base[8];                      // idx = k*2 + fsel
    #pragma unroll
    for (int k = 0; k < 4; ++k) {
        float y0  = (xb + (float)k) * r00;
        float y0s = y0 * SQH_L2E;
        float b0  = fmaf(-y0s, y0s, c0);
        float dzk = fmaf(-L20, y0, -3.5f - mz);
        float dyk = fmaf(-L10, y0, -31.5f - my);
        #pragma unroll
        for (int f = 0; f < 2; ++f) {
            float py  = f0 + (float)(32 * f);
            float y1  = (py + dyk) * r11;
            float y1s = y1 * SQH_L2E;
            base[k*2+f] = fmaf(-y1s, y1s, b0);
            urs [k*2+f] = fmaf(-L21, y1, dzk) * r22s;
        }
    }

    // ---- pass 1: exp ONCE per pixel, cache in registers, accumulate sum ----
    float ec[64];
    float acc0 = 0.f, acc1 = 0.f, acc2 = 0.f, acc3 = 0.f;
    #pragma unroll
    for (int i = 0; i < 16; ++i) {
        const int   fs = i & 1;
        const float fz = (float)(i >> 1);
        {
            float y2s = fmaf(fz, r22s, urs[0+fs]);
            float e   = exp2_fast(fmaf(-y2s, y2s, base[0+fs]));
            ec[i*4+0] = e; acc0 += e;
        }
        {
            float y2s = fmaf(fz, r22s, urs[2+fs]);
            float e   = exp2_fast(fmaf(-y2s, y2s, base[2+fs]));
            ec[i*4+1] = e; acc1 += e;
        }
        {
            float y2s = fmaf(fz, r22s, urs[4+fs]);
            float e   = exp2_fast(fmaf(-y2s, y2s, base[4+fs]));
            ec[i*4+2] = e; acc2 += e;
        }
        {
            float y2s = fmaf(fz, r22s, urs[6+fs]);
            float e   = exp2_fast(fmaf(-y2s, y2s, base[6+fs]));
            ec[i*4+3] = e; acc3 += e;
        }
    }
    float lsum = (acc0 + acc1) + (acc2 + acc3);
    #pragma unroll
    for (int off = 32; off >= 1; off >>= 1)
        lsum += __shfl_xor(lsum, off, 64);
    if ((t & 63) == 0) s_red[t >> 6] = lsum;
    __syncthreads();
    float S = 0.0f;
    #pragma unroll
    for (int k = 0; k < 8; ++k) S += s_red[k];
    const float scale = 1.0f / (S + 1e-10f);

    // ---- pass 2: scale cached values, NONTEMPORAL float4 stores ----
    f4v* op4 = (f4v*)(out + (size_t)g * NPIX) + t;
    #pragma unroll
    for (int i = 0; i < 16; ++i) {
        f4v o;
        o.x = ec[i*4+0] * scale;
        o.y = ec[i*4+1] * scale;
        o.z = ec[i*4+2] * scale;
        o.w = ec[i*4+3] * scale;
        __builtin_nontemporal_store(o, op4 + i * 512);   // pixel block p = 4t + 2048*i
    }
}

extern "C" void kernel_launch(void* const* d_in, const int* in_sizes, int n_in,
                              void* d_out, int out_size, void* d_ws, size_t ws_size,
                              hipStream_t stream) {
    const float* rep     = (const float*)d_in[0];
    const float* mean_W  = (const float*)d_in[1];
    const float* mean_b  = (const float*)d_in[2];
    const float* scale_W = (const float*)d_in[3];
    const float* scale_b = (const float*)d_in[4];
    float* out = (float*)d_out;

    hipLaunchKernelGGL(mvn_profile_kernel, dim3(NG), dim3(BLOCK), 0, stream,
                       rep, mean_W, mean_b, scale_W, scale_b, out);
}